// Round 5
// baseline (388.898 us; speedup 1.0000x reference)
//
#include <hip/hip_runtime.h>
#include <stdint.h>

typedef unsigned int u32;
typedef _Float16 f16;
typedef __attribute__((ext_vector_type(8))) _Float16 f16x8;
typedef __attribute__((ext_vector_type(4))) float f32x4;
typedef __attribute__((ext_vector_type(2))) float f32x2;

#define XMS 168   // f16 stride for X rows (336B)
#define HS  136   // f16 stride for H1 / H2 rows (272B)

// ---- workspace layout (bytes) ----
#define WOFF_WEFF 0u          // 5*32*32*2    = 10240
#define WOFF_W1SW 10240u      // 5*128*32*2   = 40960
#define WOFF_W2SW 51200u      // 4*128*32*2   = 32768
#define WOFF_W3SW 83968u      // 4*16*32*2    = 4096
#define WOFF_VD   88064u      // 48*4         = 192
#define WOFF_TM   131072u     // 3*300*300*64 = 17280000 (fp8)
#define WOFF_XG   17411072u   // 524288*160*2 = 167772160 (f16 mlp_in)
#define WS_SPLIT  185183232u
#define WS_NEED   17411072u

#define TBL_SCALE 64.0f
#define TBL_INV   (1.0f/64.0f)

// ================= prep: swizzled f16 weights (1/64 folded) =================
__global__ void prep_k(const float* __restrict__ feat_w,
                       const float* __restrict__ vmc_vec,
                       const float* __restrict__ vmd_vec,
                       const float* __restrict__ w1,
                       const float* __restrict__ w2,
                       const float* __restrict__ w3,
                       f16* __restrict__ Weff, f16* __restrict__ W1sw,
                       f16* __restrict__ W2sw, f16* __restrict__ W3sw,
                       float* __restrict__ vd)
{
  const int N_WEFF = 5120, N_W1 = 20480, N_W2 = 16384, N_W3 = 2048, N_VD = 48;
  const int total = N_WEFF + N_W1 + N_W2 + N_W3 + N_VD;
  for (int t = blockIdx.x*blockDim.x + threadIdx.x; t < total; t += gridDim.x*blockDim.x){
    if (t < N_WEFF){
      int kb = t >> 10, n = (t >> 5) & 31, kk = t & 31, k = kb*32 + kk;
      float v = 0.f;
      if (n < 27 && k < 144)
        v = feat_w[n*144 + k] * 0.5f*(vmc_vec[k*300+149] + vmc_vec[k*300+150]) * TBL_INV;
      Weff[t] = (f16)v;
    } else if (t < N_WEFF + N_W1){
      int u = t - N_WEFF;
      int kb = u >> 12, n = (u >> 5) & 127, kk = u & 31, k = kb*32 + kk;
      W1sw[u] = (f16)((k < 150) ? w1[n*150 + k] : 0.f);
    } else if (t < N_WEFF + N_W1 + N_W2){
      int u = t - N_WEFF - N_W1;
      int kb = u >> 12, n = (u >> 5) & 127, kk = u & 31, k = kb*32 + kk;
      W2sw[u] = (f16)w2[n*128 + k];
    } else if (t < N_WEFF + N_W1 + N_W2 + N_W3){
      int u = t - N_WEFF - N_W1 - N_W2;
      int kb = u >> 9, n = (u >> 5) & 15, kk = u & 31, k = kb*32 + kk;
      W3sw[u] = (f16)((n < 3) ? w3[n*128 + k] : 0.f);
    } else {
      int k = t - N_WEFF - N_W1 - N_W2 - N_W3;
      vd[k] = 0.5f*(vmd_vec[k*300+149] + vmd_vec[k*300+150]) * TBL_INV;
    }
  }
}

// ---- pack feature channels: (3,48,300,300) f32 -> Tm[...][ch 0..47] fp8*64 ----
__global__ void pack_feat_k(const float* __restrict__ src, u32* __restrict__ dst)
{
  __shared__ float tile[48*304];
  int i = blockIdx.x / 300, y = blockIdx.x % 300;
  const float* sp = src + (size_t)i*48*90000 + (size_t)y*300;
  for (int t = threadIdx.x; t < 48*300; t += 256){
    int r = t / 300, x = t - r*300;
    tile[r*304 + x] = sp[(size_t)r*90000 + x] * TBL_SCALE;
  }
  __syncthreads();
  u32* dp = dst + (size_t)(i*300 + y)*300*16;
  for (int t = threadIdx.x; t < 300*12; t += 256){
    int x = t / 12, cg = t - x*12;
    int c = cg*4;
    u32 v = __builtin_amdgcn_cvt_pk_fp8_f32(tile[c*304+x],     tile[(c+1)*304+x], 0, false);
    v     = __builtin_amdgcn_cvt_pk_fp8_f32(tile[(c+2)*304+x], tile[(c+3)*304+x], v, true);
    dp[x*16 + cg] = v;
  }
}

// ---- pack density channels: (3,16,300,300) f32 -> Tm[...][ch 48..63] fp8*64 ----
__global__ void pack_dens_k(const float* __restrict__ src, u32* __restrict__ dst)
{
  __shared__ float tile[16*304];
  int i = blockIdx.x / 300, y = blockIdx.x % 300;
  const float* sp = src + (size_t)i*16*90000 + (size_t)y*300;
  for (int t = threadIdx.x; t < 16*300; t += 256){
    int r = t / 300, x = t - r*300;
    tile[r*304 + x] = sp[(size_t)r*90000 + x] * TBL_SCALE;
  }
  __syncthreads();
  u32* dp = dst + (size_t)(i*300 + y)*300*16;
  for (int t = threadIdx.x; t < 300*4; t += 256){
    int x = t / 4, cg = t - x*4;
    int c = cg*4;
    u32 v = __builtin_amdgcn_cvt_pk_fp8_f32(tile[c*304+x],     tile[(c+1)*304+x], 0, false);
    v     = __builtin_amdgcn_cvt_pk_fp8_f32(tile[(c+2)*304+x], tile[(c+3)*304+x], v, true);
    dp[x*16 + 12 + cg] = v;
  }
}

__device__ __forceinline__ void decode16(uint4 q, float* o){
  f32x2 t;
  t = __builtin_amdgcn_cvt_pk_f32_fp8(q.x, false); o[0]=t[0];  o[1]=t[1];
  t = __builtin_amdgcn_cvt_pk_f32_fp8(q.x, true ); o[2]=t[0];  o[3]=t[1];
  t = __builtin_amdgcn_cvt_pk_f32_fp8(q.y, false); o[4]=t[0];  o[5]=t[1];
  t = __builtin_amdgcn_cvt_pk_f32_fp8(q.y, true ); o[6]=t[0];  o[7]=t[1];
  t = __builtin_amdgcn_cvt_pk_f32_fp8(q.z, false); o[8]=t[0];  o[9]=t[1];
  t = __builtin_amdgcn_cvt_pk_f32_fp8(q.z, true ); o[10]=t[0]; o[11]=t[1];
  t = __builtin_amdgcn_cvt_pk_f32_fp8(q.w, false); o[12]=t[0]; o[13]=t[1];
  t = __builtin_amdgcn_cvt_pk_f32_fp8(q.w, true ); o[14]=t[0]; o[15]=t[1];
}

// ---- shared device code: Phase A sampling + Phase B fold/PE into buf ----
__device__ __forceinline__ void sample_and_fold(
    const float* __restrict__ xin, const f16* __restrict__ WeffSw,
    const float* __restrict__ vd, const uint4* __restrict__ Tm,
    float* __restrict__ out, f16* buf, float* dLds,
    int tid, int l, int w, size_t nidx)
{
  const float* xp = xin + nidx*6;
  float p0 = xp[0], p1 = xp[1], p2 = xp[2];

  float dd0=0.f, dd1=0.f, dd2=0.f;
  if (l < 16){
    const float* dp = xin + (nidx - l + w*16 + l)*6 + 3;   // row w*16+l of this tile
    dd0 = dp[0]; dd1 = dp[1]; dd2 = dp[2];
  }

  if (w < 3){
    float cx = (w==0)? p1 : ((w==1)? p2 : p0);
    float cy = (w==0)? p2 : ((w==1)? p0 : p1);
    float fx = (cx+1.f)*0.5f*299.f, fy = (cy+1.f)*0.5f*299.f;
    float x0f = floorf(fx), y0f = floorf(fy);
    int x0 = min(max((int)x0f,0),299), y0 = min(max((int)y0f,0),299);
    int x1 = min(x0+1,299), y1 = min(y0+1,299);
    float wx = fx-x0f, wy = fy-y0f;
    float w11 = wx*wy, w10 = wy - w11, w01 = wx - w11, w00 = 1.f - wx - wy + w11;

    const uint4* Tb = Tm + (size_t)w*90000*4;
    const uint4* r00 = Tb + (size_t)(y0*300+x0)*4;
    const uint4* r01 = Tb + (size_t)(y0*300+x1)*4;
    const uint4* r10 = Tb + (size_t)(y1*300+x0)*4;
    const uint4* r11 = Tb + (size_t)(y1*300+x1)*4;
    uint4 qa[4], qb[4], qc[4], qd[4];
#pragma unroll
    for (int c4=0;c4<4;++c4){ qa[c4]=r00[c4]; qb[c4]=r01[c4]; qc[c4]=r10[c4]; qd[c4]=r11[c4]; }

    float vdw[16];
#pragma unroll
    for (int j=0;j<16;++j) vdw[j] = vd[w*16 + j];

    f16* dstrow = buf + l*XMS + w*48;
    float dacc = 0.f;
#pragma unroll
    for (int c4=0;c4<4;++c4){
      float A[16],B[16],C[16],D[16];
      decode16(qa[c4],A); decode16(qb[c4],B); decode16(qc[c4],C); decode16(qd[c4],D);
      if (c4 < 3){
        f16x8 o0, o1;
#pragma unroll
        for (int j=0;j<8;++j)
          o0[j] = (f16)(w00*A[j] + w01*B[j] + w10*C[j] + w11*D[j]);
#pragma unroll
        for (int j=0;j<8;++j)
          o1[j] = (f16)(w00*A[8+j] + w01*B[8+j] + w10*C[8+j] + w11*D[8+j]);
        *(f16x8*)(dstrow + c4*16)     = o0;
        *(f16x8*)(dstrow + c4*16 + 8) = o1;
      } else {
#pragma unroll
        for (int j=0;j<16;++j)
          dacc += (w00*A[j] + w01*B[j] + w10*C[j] + w11*D[j]) * vdw[j];
      }
    }
    dLds[w*64 + l] = dacc;
  } else {
    f16x8 z = 0;
    *(f16x8*)(buf + l*XMS + 144) = z;
    *(f16x8*)(buf + l*XMS + 152) = z;
  }
  __syncthreads();

  const int tr = l & 15;
  const int ko = (l >> 4) * 8;

  // Phase B: fold MFMA (in-place) + PE
  if (w == 3){
    float ds = dLds[l] + dLds[64 + l] + dLds[128 + l];
    out[nidx*4 + 3] = fmaxf(ds, 0.f);
  }
  f32x4 fa0 = {0.f,0.f,0.f,0.f}, fa1 = {0.f,0.f,0.f,0.f};
  const f16* Arow = buf + (w*16 + tr)*XMS + ko;
#pragma unroll
  for (int kb=0; kb<5; ++kb){
    f16x8 a  = *(const f16x8*)(Arow + kb*32);
    f16x8 b0 = *(const f16x8*)(WeffSw + (size_t)(kb*32 + tr)*32 + ko);
    f16x8 b1 = *(const f16x8*)(WeffSw + (size_t)(kb*32 + 16 + tr)*32 + ko);
    fa0 = __builtin_amdgcn_mfma_f32_16x16x32_f16(a, b0, fa0, 0,0,0);
    fa1 = __builtin_amdgcn_mfma_f32_16x16x32_f16(a, b1, fa1, 0,0,0);
  }
  __builtin_amdgcn_sched_barrier(0);
  asm volatile("" : "+v"(dd0), "+v"(dd1), "+v"(dd2) : "v"(fa0[0]));

  const int sbase = w*16 + (l>>4)*4;
#pragma unroll
  for (int nb=0; nb<2; ++nb){
    int f = nb*16 + tr;
    if (f < 27){
#pragma unroll
      for (int r=0;r<4;++r){
        float fv = nb ? fa1[r] : fa0[r];
        f16* Xr = buf + (sbase + r)*XMS;
        Xr[f] = (f16)fv;
        float a1 = 3.14159265358979f*fv;
        float a2 = 6.28318530717959f*fv;
        Xr[30+f]  = (f16)__sinf(a1);
        Xr[57+f]  = (f16)__cosf(a1);
        Xr[84+f]  = (f16)__sinf(a2);
        Xr[111+f] = (f16)__cosf(a2);
      }
    }
  }
  if (l < 16){
    f16* Xr = buf + (w*16 + l)*XMS;
    Xr[27]=(f16)dd0; Xr[28]=(f16)dd1; Xr[29]=(f16)dd2;
    float dv[3]={dd0,dd1,dd2};
#pragma unroll
    for (int j=0;j<3;++j){
      float a1=3.14159265358979f*dv[j], a2=6.28318530717959f*dv[j];
      Xr[138+j]=(f16)__sinf(a1);
      Xr[141+j]=(f16)__cosf(a1);
      Xr[144+j]=(f16)__sinf(a2);
      Xr[147+j]=(f16)__cosf(a2);
    }
  }
}

// ================= split kernel 1: gather + fold + PE -> Xg =================
__global__ __launch_bounds__(256, 6)
void gather_k(const float* __restrict__ xin,
              const f16* __restrict__ WeffSw, const float* __restrict__ vd,
              const uint4* __restrict__ Tm, f16* __restrict__ Xg,
              float* __restrict__ out)
{
  __shared__ __align__(16) f16 buf[64*XMS];
  __shared__ float dLds[192];
  const int tid = threadIdx.x;
  const int l = tid & 63, w = tid >> 6;
  const size_t nidx = (size_t)blockIdx.x*64 + l;

  sample_and_fold(xin, WeffSw, vd, Tm, out, buf, dLds, tid, l, w, nidx);
  __syncthreads();

  // copy assembled X rows (160 f16) to global
  f16* dst = Xg + (size_t)blockIdx.x*64*160;
#pragma unroll
  for (int it=0; it<5; ++it){
    int i = tid + it*256;
    int row = i / 20, q = i - row*20;
    *(f16x8*)(dst + row*160 + q*8) = *(const f16x8*)(buf + row*XMS + q*8);
  }
}

// ================= split kernel 2: MLP =================
__global__ __launch_bounds__(256, 4)
void mlp_k(const f16* __restrict__ Xg,
           const f16* __restrict__ W1sw, const f16* __restrict__ W2sw,
           const f16* __restrict__ W3sw,
           const float* __restrict__ b1v, const float* __restrict__ b2v,
           const float* __restrict__ b3v, float* __restrict__ out)
{
  __shared__ __align__(16) f16 buf[64*XMS];    // X, later H2 (stride HS)
  __shared__ __align__(16) f16 bufH[64*HS];    // H1
  const int tid = threadIdx.x;
  const int l = tid & 63, w = tid >> 6;

  // load X tile
  const f16* src = Xg + (size_t)blockIdx.x*64*160;
#pragma unroll
  for (int it=0; it<5; ++it){
    int i = tid + it*256;
    int row = i / 20, q = i - row*20;
    *(f16x8*)(buf + row*XMS + q*8) = *(const f16x8*)(src + row*160 + q*8);
  }
  __syncthreads();

  const int tr = l & 15;
  const int ko = (l >> 4) * 8;

  // layer1 (64x160 * 160x128)
  {
    f32x4 acc[4][2];
#pragma unroll
    for (int m=0;m<4;++m){ acc[m][0]=(f32x4){0.f,0.f,0.f,0.f}; acc[m][1]=(f32x4){0.f,0.f,0.f,0.f}; }
    const int n0 = w*32 + tr;
#pragma unroll
    for (int kb=0; kb<5; ++kb){
      f16x8 b0 = *(const f16x8*)(W1sw + (size_t)(kb*128 + n0)*32 + ko);
      f16x8 b1 = *(const f16x8*)(W1sw + (size_t)(kb*128 + n0 + 16)*32 + ko);
#pragma unroll
      for (int m=0;m<4;++m){
        f16x8 a = *(const f16x8*)(buf + (m*16 + tr)*XMS + kb*32 + ko);
        acc[m][0] = __builtin_amdgcn_mfma_f32_16x16x32_f16(a, b0, acc[m][0], 0,0,0);
        acc[m][1] = __builtin_amdgcn_mfma_f32_16x16x32_f16(a, b1, acc[m][1], 0,0,0);
      }
    }
    float bb0 = b1v[n0], bb1 = b1v[n0+16];
#pragma unroll
    for (int m=0;m<4;++m){
#pragma unroll
      for (int r=0;r<4;++r){
        int ss = m*16 + (l>>4)*4 + r;
        bufH[ss*HS + n0]      = (f16)fmaxf(acc[m][0][r] + bb0, 0.f);
        bufH[ss*HS + n0 + 16] = (f16)fmaxf(acc[m][1][r] + bb1, 0.f);
      }
    }
  }
  __syncthreads();

  // layer2 (64x128 * 128x128), H2 overlays X buffer
  {
    f32x4 acc[4][2];
#pragma unroll
    for (int m=0;m<4;++m){ acc[m][0]=(f32x4){0.f,0.f,0.f,0.f}; acc[m][1]=(f32x4){0.f,0.f,0.f,0.f}; }
    const int n0 = w*32 + tr;
#pragma unroll
    for (int kb=0; kb<4; ++kb){
      f16x8 b0 = *(const f16x8*)(W2sw + (size_t)(kb*128 + n0)*32 + ko);
      f16x8 b1 = *(const f16x8*)(W2sw + (size_t)(kb*128 + n0 + 16)*32 + ko);
#pragma unroll
      for (int m=0;m<4;++m){
        f16x8 a = *(const f16x8*)(bufH + (m*16 + tr)*HS + kb*32 + ko);
        acc[m][0] = __builtin_amdgcn_mfma_f32_16x16x32_f16(a, b0, acc[m][0], 0,0,0);
        acc[m][1] = __builtin_amdgcn_mfma_f32_16x16x32_f16(a, b1, acc[m][1], 0,0,0);
      }
    }
    float bb0 = b2v[n0], bb1 = b2v[n0+16];
#pragma unroll
    for (int m=0;m<4;++m){
#pragma unroll
      for (int r=0;r<4;++r){
        int ss = m*16 + (l>>4)*4 + r;
        buf[ss*HS + n0]      = (f16)fmaxf(acc[m][0][r] + bb0, 0.f);
        buf[ss*HS + n0 + 16] = (f16)fmaxf(acc[m][1][r] + bb1, 0.f);
      }
    }
  }
  __syncthreads();

  // layer3 + sigmoid
  {
    f32x4 acc = {0.f,0.f,0.f,0.f};
#pragma unroll
    for (int kb=0; kb<4; ++kb){
      f16x8 a = *(const f16x8*)(buf + (w*16 + tr)*HS + kb*32 + ko);
      f16x8 b = *(const f16x8*)(W3sw + (size_t)(kb*16 + tr)*32 + ko);
      acc = __builtin_amdgcn_mfma_f32_16x16x32_f16(a, b, acc, 0,0,0);
    }
    if (tr < 3){
      float bb = b3v[tr];
#pragma unroll
      for (int r=0;r<4;++r){
        int ss = w*16 + (l>>4)*4 + r;
        float c = acc[r] + bb;
        out[((size_t)blockIdx.x*64 + ss)*4 + tr] = 1.f/(1.f + __expf(-c));
      }
    }
  }
}

// ================= fallback: fused kernel (R4) =================
__global__ __launch_bounds__(256, 4)
void main_k(const float* __restrict__ xin,
            const f16* __restrict__ WeffSw, const f16* __restrict__ W1sw,
            const f16* __restrict__ W2sw, const f16* __restrict__ W3sw,
            const float* __restrict__ vd,
            const uint4* __restrict__ Tm,
            const float* __restrict__ b1v, const float* __restrict__ b2v,
            const float* __restrict__ b3v, float* __restrict__ out)
{
  __shared__ __align__(16) f16 buf[64*XMS];
  __shared__ __align__(16) f16 bufH[64*HS];
  __shared__ float dLds[192];

  const int tid = threadIdx.x;
  const int l = tid & 63, w = tid >> 6;
  const size_t nidx = (size_t)blockIdx.x*64 + l;

  sample_and_fold(xin, WeffSw, vd, Tm, out, buf, dLds, tid, l, w, nidx);
  __syncthreads();

  const int tr = l & 15;
  const int ko = (l >> 4) * 8;

  {
    f32x4 acc[4][2];
#pragma unroll
    for (int m=0;m<4;++m){ acc[m][0]=(f32x4){0.f,0.f,0.f,0.f}; acc[m][1]=(f32x4){0.f,0.f,0.f,0.f}; }
    const int n0 = w*32 + tr;
#pragma unroll
    for (int kb=0; kb<5; ++kb){
      f16x8 b0 = *(const f16x8*)(W1sw + (size_t)(kb*128 + n0)*32 + ko);
      f16x8 b1 = *(const f16x8*)(W1sw + (size_t)(kb*128 + n0 + 16)*32 + ko);
#pragma unroll
      for (int m=0;m<4;++m){
        f16x8 a = *(const f16x8*)(buf + (m*16 + tr)*XMS + kb*32 + ko);
        acc[m][0] = __builtin_amdgcn_mfma_f32_16x16x32_f16(a, b0, acc[m][0], 0,0,0);
        acc[m][1] = __builtin_amdgcn_mfma_f32_16x16x32_f16(a, b1, acc[m][1], 0,0,0);
      }
    }
    float bb0 = b1v[n0], bb1 = b1v[n0+16];
#pragma unroll
    for (int m=0;m<4;++m){
#pragma unroll
      for (int r=0;r<4;++r){
        int ss = m*16 + (l>>4)*4 + r;
        bufH[ss*HS + n0]      = (f16)fmaxf(acc[m][0][r] + bb0, 0.f);
        bufH[ss*HS + n0 + 16] = (f16)fmaxf(acc[m][1][r] + bb1, 0.f);
      }
    }
  }
  __syncthreads();
  {
    f32x4 acc[4][2];
#pragma unroll
    for (int m=0;m<4;++m){ acc[m][0]=(f32x4){0.f,0.f,0.f,0.f}; acc[m][1]=(f32x4){0.f,0.f,0.f,0.f}; }
    const int n0 = w*32 + tr;
#pragma unroll
    for (int kb=0; kb<4; ++kb){
      f16x8 b0 = *(const f16x8*)(W2sw + (size_t)(kb*128 + n0)*32 + ko);
      f16x8 b1 = *(const f16x8*)(W2sw + (size_t)(kb*128 + n0 + 16)*32 + ko);
#pragma unroll
      for (int m=0;m<4;++m){
        f16x8 a = *(const f16x8*)(bufH + (m*16 + tr)*HS + kb*32 + ko);
        acc[m][0] = __builtin_amdgcn_mfma_f32_16x16x32_f16(a, b0, acc[m][0], 0,0,0);
        acc[m][1] = __builtin_amdgcn_mfma_f32_16x16x32_f16(a, b1, acc[m][1], 0,0,0);
      }
    }
    float bb0 = b2v[n0], bb1 = b2v[n0+16];
#pragma unroll
    for (int m=0;m<4;++m){
#pragma unroll
      for (int r=0;r<4;++r){
        int ss = m*16 + (l>>4)*4 + r;
        buf[ss*HS + n0]      = (f16)fmaxf(acc[m][0][r] + bb0, 0.f);
        buf[ss*HS + n0 + 16] = (f16)fmaxf(acc[m][1][r] + bb1, 0.f);
      }
    }
  }
  __syncthreads();
  {
    f32x4 acc = {0.f,0.f,0.f,0.f};
#pragma unroll
    for (int kb=0; kb<4; ++kb){
      f16x8 a = *(const f16x8*)(buf + (w*16 + tr)*HS + kb*32 + ko);
      f16x8 b = *(const f16x8*)(W3sw + (size_t)(kb*16 + tr)*32 + ko);
      acc = __builtin_amdgcn_mfma_f32_16x16x32_f16(a, b, acc, 0,0,0);
    }
    if (tr < 3){
      float bb = b3v[tr];
#pragma unroll
      for (int r=0;r<4;++r){
        int ss = w*16 + (l>>4)*4 + r;
        float c = acc[r] + bb;
        out[((size_t)blockIdx.x*64 + ss)*4 + tr] = 1.f/(1.f + __expf(-c));
      }
    }
  }
}

extern "C" void kernel_launch(void* const* d_in, const int* in_sizes, int n_in,
                              void* d_out, int out_size, void* d_ws, size_t ws_size,
                              hipStream_t stream)
{
  const float* xin     = (const float*)d_in[0];
  const float* vmc_vec = (const float*)d_in[1];
  const float* vmc_mat = (const float*)d_in[2];
  const float* vmd_vec = (const float*)d_in[3];
  const float* vmd_mat = (const float*)d_in[4];
  const float* feat_w  = (const float*)d_in[5];
  const float* w1      = (const float*)d_in[6];
  const float* b1      = (const float*)d_in[7];
  const float* w2      = (const float*)d_in[8];
  const float* b2      = (const float*)d_in[9];
  const float* w3      = (const float*)d_in[10];
  const float* b3      = (const float*)d_in[11];
  float* out = (float*)d_out;

  char* ws = (char*)d_ws;
  f16*   Weff = (f16*)(ws + WOFF_WEFF);
  f16*   W1sw = (f16*)(ws + WOFF_W1SW);
  f16*   W2sw = (f16*)(ws + WOFF_W2SW);
  f16*   W3sw = (f16*)(ws + WOFF_W3SW);
  float* vd   = (float*)(ws + WOFF_VD);
  u32*   Tm   = (u32*)(ws + WOFF_TM);
  f16*   Xg   = (f16*)(ws + WOFF_XG);

  prep_k<<<64, 256, 0, stream>>>(feat_w, vmc_vec, vmd_vec, w1, w2, w3,
                                 Weff, W1sw, W2sw, W3sw, vd);
  pack_feat_k<<<900, 256, 0, stream>>>(vmc_mat, Tm);
  pack_dens_k<<<900, 256, 0, stream>>>(vmd_mat, Tm);

  if (ws_size >= (size_t)WS_SPLIT){
    gather_k<<<8192, 256, 0, stream>>>(xin, Weff, vd, (const uint4*)Tm, Xg, out);
    mlp_k<<<8192, 256, 0, stream>>>(Xg, W1sw, W2sw, W3sw, b1, b2, b3, out);
  } else {
    main_k<<<8192, 256, 0, stream>>>(xin, Weff, W1sw, W2sw, W3sw, vd,
                                     (const uint4*)Tm, b1, b2, b3, out);
  }
}

// Round 6
// 365.961 us; speedup vs baseline: 1.0627x; 1.0627x over previous
//
#include <hip/hip_runtime.h>
#include <stdint.h>

typedef unsigned int u32;
typedef _Float16 f16;
typedef __attribute__((ext_vector_type(8))) _Float16 f16x8;
typedef __attribute__((ext_vector_type(4))) float f32x4;
typedef __attribute__((ext_vector_type(2))) float f32x2;

#define XMS 168   // f16 stride for all LDS rows (336B, 2-way-free bank pattern)

// ---- workspace layout (bytes) ----
#define WOFF_WEFF 0u          // 5*32*32*2    = 10240
#define WOFF_W1SW 10240u      // 5*128*32*2   = 40960
#define WOFF_W2SW 51200u      // 4*128*32*2   = 32768
#define WOFF_W3SW 83968u      // 4*16*32*2    = 4096
#define WOFF_VD   88064u      // 48*4         = 192
#define WOFF_TM   131072u     // 3*300*300*64 = 17280000 (fp8)
#define WS_NEED   17411072u

#define TBL_SCALE 64.0f
#define TBL_INV   (1.0f/64.0f)

// ================= prep: swizzled f16 weights (1/64 folded) =================
__global__ void prep_k(const float* __restrict__ feat_w,
                       const float* __restrict__ vmc_vec,
                       const float* __restrict__ vmd_vec,
                       const float* __restrict__ w1,
                       const float* __restrict__ w2,
                       const float* __restrict__ w3,
                       f16* __restrict__ Weff, f16* __restrict__ W1sw,
                       f16* __restrict__ W2sw, f16* __restrict__ W3sw,
                       float* __restrict__ vd)
{
  const int N_WEFF = 5120, N_W1 = 20480, N_W2 = 16384, N_W3 = 2048, N_VD = 48;
  const int total = N_WEFF + N_W1 + N_W2 + N_W3 + N_VD;
  for (int t = blockIdx.x*blockDim.x + threadIdx.x; t < total; t += gridDim.x*blockDim.x){
    if (t < N_WEFF){
      int kb = t >> 10, n = (t >> 5) & 31, kk = t & 31, k = kb*32 + kk;
      float v = 0.f;
      if (n < 27 && k < 144)
        v = feat_w[n*144 + k] * 0.5f*(vmc_vec[k*300+149] + vmc_vec[k*300+150]) * TBL_INV;
      Weff[t] = (f16)v;
    } else if (t < N_WEFF + N_W1){
      int u = t - N_WEFF;
      int kb = u >> 12, n = (u >> 5) & 127, kk = u & 31, k = kb*32 + kk;
      W1sw[u] = (f16)((k < 150) ? w1[n*150 + k] : 0.f);
    } else if (t < N_WEFF + N_W1 + N_W2){
      int u = t - N_WEFF - N_W1;
      int kb = u >> 12, n = (u >> 5) & 127, kk = u & 31, k = kb*32 + kk;
      W2sw[u] = (f16)w2[n*128 + k];
    } else if (t < N_WEFF + N_W1 + N_W2 + N_W3){
      int u = t - N_WEFF - N_W1 - N_W2;
      int kb = u >> 9, n = (u >> 5) & 15, kk = u & 31, k = kb*32 + kk;
      W3sw[u] = (f16)((n < 3) ? w3[n*128 + k] : 0.f);
    } else {
      int k = t - N_WEFF - N_W1 - N_W2 - N_W3;
      vd[k] = 0.5f*(vmd_vec[k*300+149] + vmd_vec[k*300+150]) * TBL_INV;
    }
  }
}

// ---- pack feature channels: (3,48,300,300) f32 -> Tm[...][ch 0..47] fp8*64 ----
__global__ void pack_feat_k(const float* __restrict__ src, u32* __restrict__ dst)
{
  __shared__ float tile[48*304];
  int i = blockIdx.x / 300, y = blockIdx.x % 300;
  const float* sp = src + (size_t)i*48*90000 + (size_t)y*300;
  for (int t = threadIdx.x; t < 48*300; t += 256){
    int r = t / 300, x = t - r*300;
    tile[r*304 + x] = sp[(size_t)r*90000 + x] * TBL_SCALE;
  }
  __syncthreads();
  u32* dp = dst + (size_t)(i*300 + y)*300*16;
  for (int t = threadIdx.x; t < 300*12; t += 256){
    int x = t / 12, cg = t - x*12;
    int c = cg*4;
    u32 v = __builtin_amdgcn_cvt_pk_fp8_f32(tile[c*304+x],     tile[(c+1)*304+x], 0, false);
    v     = __builtin_amdgcn_cvt_pk_fp8_f32(tile[(c+2)*304+x], tile[(c+3)*304+x], v, true);
    dp[x*16 + cg] = v;
  }
}

// ---- pack density channels: (3,16,300,300) f32 -> Tm[...][ch 48..63] fp8*64 ----
__global__ void pack_dens_k(const float* __restrict__ src, u32* __restrict__ dst)
{
  __shared__ float tile[16*304];
  int i = blockIdx.x / 300, y = blockIdx.x % 300;
  const float* sp = src + (size_t)i*16*90000 + (size_t)y*300;
  for (int t = threadIdx.x; t < 16*300; t += 256){
    int r = t / 300, x = t - r*300;
    tile[r*304 + x] = sp[(size_t)r*90000 + x] * TBL_SCALE;
  }
  __syncthreads();
  u32* dp = dst + (size_t)(i*300 + y)*300*16;
  for (int t = threadIdx.x; t < 300*4; t += 256){
    int x = t / 4, cg = t - x*4;
    int c = cg*4;
    u32 v = __builtin_amdgcn_cvt_pk_fp8_f32(tile[c*304+x],     tile[(c+1)*304+x], 0, false);
    v     = __builtin_amdgcn_cvt_pk_fp8_f32(tile[(c+2)*304+x], tile[(c+3)*304+x], v, true);
    dp[x*16 + 12 + cg] = v;
  }
}

__device__ __forceinline__ void decode16(uint4 q, float* o){
  f32x2 t;
  t = __builtin_amdgcn_cvt_pk_f32_fp8(q.x, false); o[0]=t[0];  o[1]=t[1];
  t = __builtin_amdgcn_cvt_pk_f32_fp8(q.x, true ); o[2]=t[0];  o[3]=t[1];
  t = __builtin_amdgcn_cvt_pk_f32_fp8(q.y, false); o[4]=t[0];  o[5]=t[1];
  t = __builtin_amdgcn_cvt_pk_f32_fp8(q.y, true ); o[6]=t[0];  o[7]=t[1];
  t = __builtin_amdgcn_cvt_pk_f32_fp8(q.z, false); o[8]=t[0];  o[9]=t[1];
  t = __builtin_amdgcn_cvt_pk_f32_fp8(q.z, true ); o[10]=t[0]; o[11]=t[1];
  t = __builtin_amdgcn_cvt_pk_f32_fp8(q.w, false); o[12]=t[0]; o[13]=t[1];
  t = __builtin_amdgcn_cvt_pk_f32_fp8(q.w, true ); o[14]=t[0]; o[15]=t[1];
}

// ================= fused kernel, single LDS buffer, 7 blocks/CU =================
__global__ __launch_bounds__(256, 7)
void main_k(const float* __restrict__ xin,
            const f16* __restrict__ WeffSw, const f16* __restrict__ W1sw,
            const f16* __restrict__ W2sw, const f16* __restrict__ W3sw,
            const float* __restrict__ vd,
            const uint4* __restrict__ Tm,
            const float* __restrict__ b1v, const float* __restrict__ b2v,
            const float* __restrict__ b3v, float* __restrict__ out)
{
  // one buffer for everything: Xm -> X (in-place) -> H1 (in-place) -> H2 (in-place)
  __shared__ __align__(16) f16 buf[64*XMS];
  __shared__ float dLds[192];

  const int tid = threadIdx.x;
  const int l = tid & 63;
  const int w = tid >> 6;
  const size_t nidx = (size_t)blockIdx.x*64 + l;

  const float* xp = xin + nidx*6;
  float p0 = xp[0], p1 = xp[1], p2 = xp[2];

  // preload dirs for the row this (wave, lane<16) will own in Phase B
  float dd0=0.f, dd1=0.f, dd2=0.f;
  if (l < 16){
    const float* dp = xin + ((size_t)blockIdx.x*64 + w*16 + l)*6 + 3;
    dd0 = dp[0]; dd1 = dp[1]; dd2 = dp[2];
  }

  // ---------------- Phase A: sampling (waves 0..2, one plane each) ----------------
  if (w < 3){
    float cx = (w==0)? p1 : ((w==1)? p2 : p0);
    float cy = (w==0)? p2 : ((w==1)? p0 : p1);
    float fx = (cx+1.f)*0.5f*299.f, fy = (cy+1.f)*0.5f*299.f;
    float x0f = floorf(fx), y0f = floorf(fy);
    int x0 = min(max((int)x0f,0),299), y0 = min(max((int)y0f,0),299);
    int x1 = min(x0+1,299), y1 = min(y0+1,299);
    float wx = fx-x0f, wy = fy-y0f;
    float w11 = wx*wy, w10 = wy - w11, w01 = wx - w11, w00 = 1.f - wx - wy + w11;

    const uint4* Tb = Tm + (size_t)w*90000*4;
    const uint4* r00 = Tb + (size_t)(y0*300+x0)*4;
    const uint4* r01 = Tb + (size_t)(y0*300+x1)*4;
    const uint4* r10 = Tb + (size_t)(y1*300+x0)*4;
    const uint4* r11 = Tb + (size_t)(y1*300+x1)*4;
    uint4 qa[4], qb[4], qc[4], qd[4];
#pragma unroll
    for (int c4=0;c4<4;++c4){ qa[c4]=r00[c4]; qb[c4]=r01[c4]; qc[c4]=r10[c4]; qd[c4]=r11[c4]; }

    float vdw[16];
#pragma unroll
    for (int j=0;j<16;++j) vdw[j] = vd[w*16 + j];

    f16* dstrow = buf + l*XMS + w*48;
    float dacc = 0.f;
#pragma unroll
    for (int c4=0;c4<4;++c4){
      float A[16],B[16],C[16],D[16];
      decode16(qa[c4],A); decode16(qb[c4],B); decode16(qc[c4],C); decode16(qd[c4],D);
      if (c4 < 3){
        f16x8 o0, o1;
#pragma unroll
        for (int j=0;j<8;++j)
          o0[j] = (f16)(w00*A[j] + w01*B[j] + w10*C[j] + w11*D[j]);
#pragma unroll
        for (int j=0;j<8;++j)
          o1[j] = (f16)(w00*A[8+j] + w01*B[8+j] + w10*C[8+j] + w11*D[8+j]);
        *(f16x8*)(dstrow + c4*16)     = o0;
        *(f16x8*)(dstrow + c4*16 + 8) = o1;
      } else {
#pragma unroll
        for (int j=0;j<16;++j)
          dacc += (w00*A[j] + w01*B[j] + w10*C[j] + w11*D[j]) * vdw[j];
      }
    }
    dLds[w*64 + l] = dacc;
  } else {
    // wave 3: zero K-pad cols [144..160)
    f16x8 z = 0;
    *(f16x8*)(buf + l*XMS + 144) = z;
    *(f16x8*)(buf + l*XMS + 152) = z;
  }
  __syncthreads();

  const int tr = l & 15;          // within-tile row/col
  const int ko = (l >> 4) * 8;    // k-suboffset (8 f16 per lane)

  // ---------------- Phase B: fold MFMA (in-place Xm -> X) + PE ----------------
  {
    if (w == 3){
      float ds = dLds[l] + dLds[64 + l] + dLds[128 + l];
      out[nidx*4 + 3] = fmaxf(ds, 0.f);
    }
    f32x4 fa0 = {0.f,0.f,0.f,0.f}, fa1 = {0.f,0.f,0.f,0.f};
    const f16* Arow = buf + (w*16 + tr)*XMS + ko;
#pragma unroll
    for (int kb=0; kb<5; ++kb){
      f16x8 a  = *(const f16x8*)(Arow + kb*32);
      f16x8 b0 = *(const f16x8*)(WeffSw + (size_t)(kb*32 + tr)*32 + ko);
      f16x8 b1 = *(const f16x8*)(WeffSw + (size_t)(kb*32 + 16 + tr)*32 + ko);
      fa0 = __builtin_amdgcn_mfma_f32_16x16x32_f16(a, b0, fa0, 0,0,0);
      fa1 = __builtin_amdgcn_mfma_f32_16x16x32_f16(a, b1, fa1, 0,0,0);
    }
    // pin all X writes after the fold's LDS reads (in-place safety, same-wave rows only)
    __builtin_amdgcn_sched_barrier(0);
    asm volatile("" : "+v"(dd0), "+v"(dd1), "+v"(dd2) : "v"(fa0[0]));

    const int sbase = w*16 + (l>>4)*4;
#pragma unroll
    for (int nb=0; nb<2; ++nb){
      int f = nb*16 + tr;
      if (f < 27){
#pragma unroll
        for (int r=0;r<4;++r){
          float fv = nb ? fa1[r] : fa0[r];
          f16* Xr = buf + (sbase + r)*XMS;
          Xr[f] = (f16)fv;
          float a1 = 3.14159265358979f*fv;
          float a2 = 6.28318530717959f*fv;
          Xr[30+f]  = (f16)__sinf(a1);
          Xr[57+f]  = (f16)__cosf(a1);
          Xr[84+f]  = (f16)__sinf(a2);
          Xr[111+f] = (f16)__cosf(a2);
        }
      }
    }
    if (l < 16){
      f16* Xr = buf + (w*16 + l)*XMS;
      Xr[27]=(f16)dd0; Xr[28]=(f16)dd1; Xr[29]=(f16)dd2;
      float dv[3]={dd0,dd1,dd2};
#pragma unroll
      for (int j=0;j<3;++j){
        float a1=3.14159265358979f*dv[j], a2=6.28318530717959f*dv[j];
        Xr[138+j]=(f16)__sinf(a1);
        Xr[141+j]=(f16)__cosf(a1);
        Xr[144+j]=(f16)__sinf(a2);
        Xr[147+j]=(f16)__cosf(a2);
      }
    }
  }
  __syncthreads();

  // ---------------- Phase C: layer1 (64x160 * 160x128), H1 overwrites X ----------------
  {
    f32x4 acc[4][2];
#pragma unroll
    for (int m=0;m<4;++m){ acc[m][0]=(f32x4){0.f,0.f,0.f,0.f}; acc[m][1]=(f32x4){0.f,0.f,0.f,0.f}; }
    const int n0 = w*32 + tr;
#pragma unroll
    for (int kb=0; kb<5; ++kb){
      f16x8 b0 = *(const f16x8*)(W1sw + (size_t)(kb*128 + n0)*32 + ko);
      f16x8 b1 = *(const f16x8*)(W1sw + (size_t)(kb*128 + n0 + 16)*32 + ko);
#pragma unroll
      for (int m=0;m<4;++m){
        f16x8 a = *(const f16x8*)(buf + (m*16 + tr)*XMS + kb*32 + ko);
        acc[m][0] = __builtin_amdgcn_mfma_f32_16x16x32_f16(a, b0, acc[m][0], 0,0,0);
        acc[m][1] = __builtin_amdgcn_mfma_f32_16x16x32_f16(a, b1, acc[m][1], 0,0,0);
      }
    }
    __syncthreads();   // all X reads complete before overwriting
    float bb0 = b1v[n0], bb1 = b1v[n0+16];
#pragma unroll
    for (int m=0;m<4;++m){
#pragma unroll
      for (int r=0;r<4;++r){
        int ss = m*16 + (l>>4)*4 + r;
        buf[ss*XMS + n0]      = (f16)fmaxf(acc[m][0][r] + bb0, 0.f);
        buf[ss*XMS + n0 + 16] = (f16)fmaxf(acc[m][1][r] + bb1, 0.f);
      }
    }
  }
  __syncthreads();

  // ---------------- Phase D: layer2 (64x128 * 128x128), H2 overwrites H1 ----------------
  {
    f32x4 acc[4][2];
#pragma unroll
    for (int m=0;m<4;++m){ acc[m][0]=(f32x4){0.f,0.f,0.f,0.f}; acc[m][1]=(f32x4){0.f,0.f,0.f,0.f}; }
    const int n0 = w*32 + tr;
#pragma unroll
    for (int kb=0; kb<4; ++kb){
      f16x8 b0 = *(const f16x8*)(W2sw + (size_t)(kb*128 + n0)*32 + ko);
      f16x8 b1 = *(const f16x8*)(W2sw + (size_t)(kb*128 + n0 + 16)*32 + ko);
#pragma unroll
      for (int m=0;m<4;++m){
        f16x8 a = *(const f16x8*)(buf + (m*16 + tr)*XMS + kb*32 + ko);
        acc[m][0] = __builtin_amdgcn_mfma_f32_16x16x32_f16(a, b0, acc[m][0], 0,0,0);
        acc[m][1] = __builtin_amdgcn_mfma_f32_16x16x32_f16(a, b1, acc[m][1], 0,0,0);
      }
    }
    __syncthreads();   // all H1 reads complete before overwriting
    float bb0 = b2v[n0], bb1 = b2v[n0+16];
#pragma unroll
    for (int m=0;m<4;++m){
#pragma unroll
      for (int r=0;r<4;++r){
        int ss = m*16 + (l>>4)*4 + r;
        buf[ss*XMS + n0]      = (f16)fmaxf(acc[m][0][r] + bb0, 0.f);
        buf[ss*XMS + n0 + 16] = (f16)fmaxf(acc[m][1][r] + bb1, 0.f);
      }
    }
  }
  __syncthreads();

  // ---------------- Phase E: layer3 + sigmoid ----------------
  {
    f32x4 acc = {0.f,0.f,0.f,0.f};
#pragma unroll
    for (int kb=0; kb<4; ++kb){
      f16x8 a = *(const f16x8*)(buf + (w*16 + tr)*XMS + kb*32 + ko);
      f16x8 b = *(const f16x8*)(W3sw + (size_t)(kb*16 + tr)*32 + ko);
      acc = __builtin_amdgcn_mfma_f32_16x16x32_f16(a, b, acc, 0,0,0);
    }
    if (tr < 3){
      float bb = b3v[tr];
#pragma unroll
      for (int r=0;r<4;++r){
        int ss = w*16 + (l>>4)*4 + r;
        float c = acc[r] + bb;
        out[((size_t)blockIdx.x*64 + ss)*4 + tr] = 1.f/(1.f + __expf(-c));
      }
    }
  }
}

extern "C" void kernel_launch(void* const* d_in, const int* in_sizes, int n_in,
                              void* d_out, int out_size, void* d_ws, size_t ws_size,
                              hipStream_t stream)
{
  const float* xin     = (const float*)d_in[0];
  const float* vmc_vec = (const float*)d_in[1];
  const float* vmc_mat = (const float*)d_in[2];
  const float* vmd_vec = (const float*)d_in[3];
  const float* vmd_mat = (const float*)d_in[4];
  const float* feat_w  = (const float*)d_in[5];
  const float* w1      = (const float*)d_in[6];
  const float* b1      = (const float*)d_in[7];
  const float* w2      = (const float*)d_in[8];
  const float* b2      = (const float*)d_in[9];
  const float* w3      = (const float*)d_in[10];
  const float* b3      = (const float*)d_in[11];
  float* out = (float*)d_out;

  char* ws = (char*)d_ws;
  f16*   Weff = (f16*)(ws + WOFF_WEFF);
  f16*   W1sw = (f16*)(ws + WOFF_W1SW);
  f16*   W2sw = (f16*)(ws + WOFF_W2SW);
  f16*   W3sw = (f16*)(ws + WOFF_W3SW);
  float* vd   = (float*)(ws + WOFF_VD);
  u32*   Tm   = (u32*)(ws + WOFF_TM);

  prep_k<<<64, 256, 0, stream>>>(feat_w, vmc_vec, vmd_vec, w1, w2, w3,
                                 Weff, W1sw, W2sw, W3sw, vd);
  pack_feat_k<<<900, 256, 0, stream>>>(vmc_mat, Tm);
  pack_dens_k<<<900, 256, 0, stream>>>(vmd_mat, Tm);

  main_k<<<8192, 256, 0, stream>>>(xin, Weff, W1sw, W2sw, W3sw, vd,
                                   (const uint4*)Tm, b1, b2, b3, out);
}

// Round 7
// 230.583 us; speedup vs baseline: 1.6866x; 1.5871x over previous
//
#include <hip/hip_runtime.h>
#include <stdint.h>

typedef unsigned int u32;
typedef _Float16 f16;
typedef __attribute__((ext_vector_type(8))) _Float16 f16x8;
typedef __attribute__((ext_vector_type(4))) float f32x4;
typedef __attribute__((ext_vector_type(2))) float f32x2;

#define XMS 168   // f16 stride for X rows (336B)
#define HS  136   // f16 stride for H1 / H2 rows (272B)

#define NS   524288
#define NBIN 32768

// ---- workspace layout (bytes) ----
#define WOFF_WEFF 0u          // 5*32*32*2    = 10240
#define WOFF_W1SW 10240u      // 5*128*32*2   = 40960
#define WOFF_W2SW 51200u      // 4*128*32*2   = 32768
#define WOFF_W3SW 83968u      // 4*16*32*2    = 4096
#define WOFF_VD   88064u      // 48*4         = 192
#define WOFF_TM   131072u     // 3*300*300*64 = 17280000 (fp8)
#define WOFF_HIST 17411072u   // 32768*4
#define WOFF_CUR  17542144u   // 32768*4
#define WOFF_KEYS 17673216u   // 524288*4
#define WOFF_PERM 19770368u   // 524288*4
#define WOFF_XS   21867520u   // 524288*6*4
#define WS_NEED   34450432u

#define TBL_SCALE 64.0f
#define TBL_INV   (1.0f/64.0f)

// ================= prep: swizzled f16 weights (1/64 folded) =================
__global__ void prep_k(const float* __restrict__ feat_w,
                       const float* __restrict__ vmc_vec,
                       const float* __restrict__ vmd_vec,
                       const float* __restrict__ w1,
                       const float* __restrict__ w2,
                       const float* __restrict__ w3,
                       f16* __restrict__ Weff, f16* __restrict__ W1sw,
                       f16* __restrict__ W2sw, f16* __restrict__ W3sw,
                       float* __restrict__ vd)
{
  const int N_WEFF = 5120, N_W1 = 20480, N_W2 = 16384, N_W3 = 2048, N_VD = 48;
  const int total = N_WEFF + N_W1 + N_W2 + N_W3 + N_VD;
  for (int t = blockIdx.x*blockDim.x + threadIdx.x; t < total; t += gridDim.x*blockDim.x){
    if (t < N_WEFF){
      int kb = t >> 10, n = (t >> 5) & 31, kk = t & 31, k = kb*32 + kk;
      float v = 0.f;
      if (n < 27 && k < 144)
        v = feat_w[n*144 + k] * 0.5f*(vmc_vec[k*300+149] + vmc_vec[k*300+150]) * TBL_INV;
      Weff[t] = (f16)v;
    } else if (t < N_WEFF + N_W1){
      int u = t - N_WEFF;
      int kb = u >> 12, n = (u >> 5) & 127, kk = u & 31, k = kb*32 + kk;
      W1sw[u] = (f16)((k < 150) ? w1[n*150 + k] : 0.f);
    } else if (t < N_WEFF + N_W1 + N_W2){
      int u = t - N_WEFF - N_W1;
      int kb = u >> 12, n = (u >> 5) & 127, kk = u & 31, k = kb*32 + kk;
      W2sw[u] = (f16)w2[n*128 + k];
    } else if (t < N_WEFF + N_W1 + N_W2 + N_W3){
      int u = t - N_WEFF - N_W1 - N_W2;
      int kb = u >> 9, n = (u >> 5) & 15, kk = u & 31, k = kb*32 + kk;
      W3sw[u] = (f16)((n < 3) ? w3[n*128 + k] : 0.f);
    } else {
      int k = t - N_WEFF - N_W1 - N_W2 - N_W3;
      vd[k] = 0.5f*(vmd_vec[k*300+149] + vmd_vec[k*300+150]) * TBL_INV;
    }
  }
}

// ---- pack feature+density channels into Tm[plane][y][x][64ch] fp8*64 ----
__global__ void pack_k(const float* __restrict__ feat, const float* __restrict__ dens,
                       u32* __restrict__ dst)
{
  __shared__ float tile[48*304];
  int b = blockIdx.x;
  bool isf = b < 900;
  int bb = isf ? b : b - 900;
  int i = bb / 300, y = bb % 300;
  int C = isf ? 48 : 16;
  const float* sp = (isf ? feat : dens) + (size_t)i*C*90000 + (size_t)y*300;
  for (int t = threadIdx.x; t < C*300; t += 256){
    int r = t / 300, x = t - r*300;
    tile[r*304 + x] = sp[(size_t)r*90000 + x] * TBL_SCALE;
  }
  __syncthreads();
  u32* dp = dst + (size_t)(i*300 + y)*300*16 + (isf ? 0 : 12);
  int ng = C >> 2;
  for (int t = threadIdx.x; t < 300*ng; t += 256){
    int x = t / ng, cg = t - x*ng;
    int c = cg*4;
    u32 v = __builtin_amdgcn_cvt_pk_fp8_f32(tile[c*304+x],     tile[(c+1)*304+x], 0, false);
    v     = __builtin_amdgcn_cvt_pk_fp8_f32(tile[(c+2)*304+x], tile[(c+3)*304+x], v, true);
    dp[x*16 + cg] = v;
  }
}

// ================= Morton counting sort =================
__global__ void zero_k(u32* __restrict__ h){ h[blockIdx.x*1024 + threadIdx.x] = 0u; }

__device__ __forceinline__ u32 mcell(float p){
  int c = (int)((p + 1.f)*16.f);
  return (u32)min(31, max(0, c));
}
__device__ __forceinline__ u32 morton15(u32 a, u32 b, u32 c){
  u32 r = 0;
#pragma unroll
  for (int i=0;i<5;++i)
    r |= (((a>>i)&1u)<<(3*i+2)) | (((b>>i)&1u)<<(3*i+1)) | (((c>>i)&1u)<<(3*i));
  return r;
}

__global__ void key_k(const float* __restrict__ xin, u32* __restrict__ keys,
                      u32* __restrict__ hist)
{
  int t = blockIdx.x*256 + threadIdx.x;
  const float* xp = xin + (size_t)t*6;
  u32 k = morton15(mcell(xp[0]), mcell(xp[1]), mcell(xp[2]));
  keys[t] = k;
  atomicAdd(&hist[k], 1u);
}

__global__ __launch_bounds__(1024, 1)
void scan_k(const u32* __restrict__ hist, u32* __restrict__ cur)
{
  __shared__ u32 s[1024];
  int t = threadIdx.x;
  u32 loc[32];
  u32 sum = 0;
  const u32* hp = hist + t*32;
#pragma unroll
  for (int j=0;j<32;++j){ loc[j] = sum; sum += hp[j]; }
  s[t] = sum;
  __syncthreads();
  for (int off=1; off<1024; off<<=1){
    u32 v = (t >= off) ? s[t-off] : 0u;
    __syncthreads();
    s[t] += v;
    __syncthreads();
  }
  u32 base = (t == 0) ? 0u : s[t-1];
  u32* cp = cur + t*32;
#pragma unroll
  for (int j=0;j<32;++j) cp[j] = base + loc[j];
}

__global__ void scatter_k(const float* __restrict__ xin, const u32* __restrict__ keys,
                          u32* __restrict__ cur, u32* __restrict__ perm,
                          float* __restrict__ xs)
{
  int t = blockIdx.x*256 + threadIdx.x;
  u32 k = keys[t];
  u32 pos = atomicAdd(&cur[k], 1u);
  perm[pos] = (u32)t;
  const float* sp = xin + (size_t)t*6;
  float* dp = xs + (size_t)pos*6;
  dp[0]=sp[0]; dp[1]=sp[1]; dp[2]=sp[2]; dp[3]=sp[3]; dp[4]=sp[4]; dp[5]=sp[5];
}

__device__ __forceinline__ void decode16(uint4 q, float* o){
  f32x2 t;
  t = __builtin_amdgcn_cvt_pk_f32_fp8(q.x, false); o[0]=t[0];  o[1]=t[1];
  t = __builtin_amdgcn_cvt_pk_f32_fp8(q.x, true ); o[2]=t[0];  o[3]=t[1];
  t = __builtin_amdgcn_cvt_pk_f32_fp8(q.y, false); o[4]=t[0];  o[5]=t[1];
  t = __builtin_amdgcn_cvt_pk_f32_fp8(q.y, true ); o[6]=t[0];  o[7]=t[1];
  t = __builtin_amdgcn_cvt_pk_f32_fp8(q.z, false); o[8]=t[0];  o[9]=t[1];
  t = __builtin_amdgcn_cvt_pk_f32_fp8(q.z, true ); o[10]=t[0]; o[11]=t[1];
  t = __builtin_amdgcn_cvt_pk_f32_fp8(q.w, false); o[12]=t[0]; o[13]=t[1];
  t = __builtin_amdgcn_cvt_pk_f32_fp8(q.w, true ); o[14]=t[0]; o[15]=t[1];
}

// ================= fused main kernel (R4 structure + sorted input) =================
template<bool SORTED>
__global__ __launch_bounds__(256, 4)
void main_k(const float* __restrict__ xs, const u32* __restrict__ perm,
            const f16* __restrict__ WeffSw, const f16* __restrict__ W1sw,
            const f16* __restrict__ W2sw, const f16* __restrict__ W3sw,
            const float* __restrict__ vd,
            const uint4* __restrict__ Tm,
            const float* __restrict__ b1v, const float* __restrict__ b2v,
            const float* __restrict__ b3v, float* __restrict__ out)
{
  __shared__ __align__(16) f16 buf[64*XMS];   // Xm -> X (in-place) -> H2 (stride HS)
  __shared__ __align__(16) f16 bufH[64*HS];   // H1
  __shared__ float dLds[192];

  const int tid = threadIdx.x;
  const int l = tid & 63;
  const int w = tid >> 6;

  // XCD-chunked swizzle: each XCD gets a contiguous Morton range
  const int tile = SORTED ? ((blockIdx.x & 7)*1024 + (blockIdx.x >> 3)) : blockIdx.x;
  const size_t base = (size_t)tile*64;

  const float* xp = xs + (base + l)*6;
  float p0 = xp[0], p1 = xp[1], p2 = xp[2];

  // output indices (original sample ids)
  u32 pmL = SORTED ? perm[base + l] : (u32)(base + l);
  const int ssb = w*16 + (l>>4)*4;
  u32 pmr[4];
#pragma unroll
  for (int r=0;r<4;++r)
    pmr[r] = SORTED ? perm[base + ssb + r] : (u32)(base + ssb + r);

  // preload dirs for the row this (wave, lane<16) owns in Phase B
  float dd0=0.f, dd1=0.f, dd2=0.f;
  if (l < 16){
    const float* dp = xs + (base + w*16 + l)*6 + 3;
    dd0 = dp[0]; dd1 = dp[1]; dd2 = dp[2];
  }

  // ---------------- Phase A: sampling (waves 0..2, one plane each) ----------------
  if (w < 3){
    float cx = (w==0)? p1 : ((w==1)? p2 : p0);
    float cy = (w==0)? p2 : ((w==1)? p0 : p1);
    float fx = (cx+1.f)*0.5f*299.f, fy = (cy+1.f)*0.5f*299.f;
    float x0f = floorf(fx), y0f = floorf(fy);
    int x0 = min(max((int)x0f,0),299), y0 = min(max((int)y0f,0),299);
    int x1 = min(x0+1,299), y1 = min(y0+1,299);
    float wx = fx-x0f, wy = fy-y0f;
    float w11 = wx*wy, w10 = wy - w11, w01 = wx - w11, w00 = 1.f - wx - wy + w11;

    const uint4* Tb = Tm + (size_t)w*90000*4;
    const uint4* r00 = Tb + (size_t)(y0*300+x0)*4;
    const uint4* r01 = Tb + (size_t)(y0*300+x1)*4;
    const uint4* r10 = Tb + (size_t)(y1*300+x0)*4;
    const uint4* r11 = Tb + (size_t)(y1*300+x1)*4;
    uint4 qa[4], qb[4], qc[4], qd[4];
#pragma unroll
    for (int c4=0;c4<4;++c4){ qa[c4]=r00[c4]; qb[c4]=r01[c4]; qc[c4]=r10[c4]; qd[c4]=r11[c4]; }

    float vdw[16];
#pragma unroll
    for (int j=0;j<16;++j) vdw[j] = vd[w*16 + j];

    f16* dstrow = buf + l*XMS + w*48;
    float dacc = 0.f;
#pragma unroll
    for (int c4=0;c4<4;++c4){
      float A[16],B[16],C[16],D[16];
      decode16(qa[c4],A); decode16(qb[c4],B); decode16(qc[c4],C); decode16(qd[c4],D);
      if (c4 < 3){
        f16x8 o0, o1;
#pragma unroll
        for (int j=0;j<8;++j)
          o0[j] = (f16)(w00*A[j] + w01*B[j] + w10*C[j] + w11*D[j]);
#pragma unroll
        for (int j=0;j<8;++j)
          o1[j] = (f16)(w00*A[8+j] + w01*B[8+j] + w10*C[8+j] + w11*D[8+j]);
        *(f16x8*)(dstrow + c4*16)     = o0;
        *(f16x8*)(dstrow + c4*16 + 8) = o1;
      } else {
#pragma unroll
        for (int j=0;j<16;++j)
          dacc += (w00*A[j] + w01*B[j] + w10*C[j] + w11*D[j]) * vdw[j];
      }
    }
    dLds[w*64 + l] = dacc;
  } else {
    // wave 3: zero K-pad cols [144..160)
    f16x8 z = 0;
    *(f16x8*)(buf + l*XMS + 144) = z;
    *(f16x8*)(buf + l*XMS + 152) = z;
  }
  __syncthreads();

  const int tr = l & 15;
  const int ko = (l >> 4) * 8;

  // ---------------- Phase B: fold MFMA (in-place Xm -> X) + PE ----------------
  {
    if (w == 3){
      float ds = dLds[l] + dLds[64 + l] + dLds[128 + l];
      out[(size_t)pmL*4 + 3] = fmaxf(ds, 0.f);
    }
    f32x4 fa0 = {0.f,0.f,0.f,0.f}, fa1 = {0.f,0.f,0.f,0.f};
    const f16* Arow = buf + (w*16 + tr)*XMS + ko;
#pragma unroll
    for (int kb=0; kb<5; ++kb){
      f16x8 a  = *(const f16x8*)(Arow + kb*32);
      f16x8 b0 = *(const f16x8*)(WeffSw + (size_t)(kb*32 + tr)*32 + ko);
      f16x8 b1 = *(const f16x8*)(WeffSw + (size_t)(kb*32 + 16 + tr)*32 + ko);
      fa0 = __builtin_amdgcn_mfma_f32_16x16x32_f16(a, b0, fa0, 0,0,0);
      fa1 = __builtin_amdgcn_mfma_f32_16x16x32_f16(a, b1, fa1, 0,0,0);
    }
    __builtin_amdgcn_sched_barrier(0);
    asm volatile("" : "+v"(dd0), "+v"(dd1), "+v"(dd2) : "v"(fa0[0]));

    const int sbase = ssb;
#pragma unroll
    for (int nb=0; nb<2; ++nb){
      int f = nb*16 + tr;
      if (f < 27){
#pragma unroll
        for (int r=0;r<4;++r){
          float fv = nb ? fa1[r] : fa0[r];
          f16* Xr = buf + (sbase + r)*XMS;
          Xr[f] = (f16)fv;
          float a1 = 3.14159265358979f*fv;
          float a2 = 6.28318530717959f*fv;
          Xr[30+f]  = (f16)__sinf(a1);
          Xr[57+f]  = (f16)__cosf(a1);
          Xr[84+f]  = (f16)__sinf(a2);
          Xr[111+f] = (f16)__cosf(a2);
        }
      }
    }
    if (l < 16){
      f16* Xr = buf + (w*16 + l)*XMS;
      Xr[27]=(f16)dd0; Xr[28]=(f16)dd1; Xr[29]=(f16)dd2;
      float dv[3]={dd0,dd1,dd2};
#pragma unroll
      for (int j=0;j<3;++j){
        float a1=3.14159265358979f*dv[j], a2=6.28318530717959f*dv[j];
        Xr[138+j]=(f16)__sinf(a1);
        Xr[141+j]=(f16)__cosf(a1);
        Xr[144+j]=(f16)__sinf(a2);
        Xr[147+j]=(f16)__cosf(a2);
      }
    }
  }
  __syncthreads();

  // ---------------- Phase C: layer1 (64x160 * 160x128) -> bufH ----------------
  {
    f32x4 acc[4][2];
#pragma unroll
    for (int m=0;m<4;++m){ acc[m][0]=(f32x4){0.f,0.f,0.f,0.f}; acc[m][1]=(f32x4){0.f,0.f,0.f,0.f}; }
    const int n0 = w*32 + tr;
#pragma unroll
    for (int kb=0; kb<5; ++kb){
      f16x8 b0 = *(const f16x8*)(W1sw + (size_t)(kb*128 + n0)*32 + ko);
      f16x8 b1 = *(const f16x8*)(W1sw + (size_t)(kb*128 + n0 + 16)*32 + ko);
#pragma unroll
      for (int m=0;m<4;++m){
        f16x8 a = *(const f16x8*)(buf + (m*16 + tr)*XMS + kb*32 + ko);
        acc[m][0] = __builtin_amdgcn_mfma_f32_16x16x32_f16(a, b0, acc[m][0], 0,0,0);
        acc[m][1] = __builtin_amdgcn_mfma_f32_16x16x32_f16(a, b1, acc[m][1], 0,0,0);
      }
    }
    float bb0 = b1v[n0], bb1 = b1v[n0+16];
#pragma unroll
    for (int m=0;m<4;++m){
#pragma unroll
      for (int r=0;r<4;++r){
        int ss = m*16 + (l>>4)*4 + r;
        bufH[ss*HS + n0]      = (f16)fmaxf(acc[m][0][r] + bb0, 0.f);
        bufH[ss*HS + n0 + 16] = (f16)fmaxf(acc[m][1][r] + bb1, 0.f);
      }
    }
  }
  __syncthreads();

  // ---------------- Phase D: layer2 (64x128 * 128x128), H2 overlays buf ----------------
  {
    f32x4 acc[4][2];
#pragma unroll
    for (int m=0;m<4;++m){ acc[m][0]=(f32x4){0.f,0.f,0.f,0.f}; acc[m][1]=(f32x4){0.f,0.f,0.f,0.f}; }
    const int n0 = w*32 + tr;
#pragma unroll
    for (int kb=0; kb<4; ++kb){
      f16x8 b0 = *(const f16x8*)(W2sw + (size_t)(kb*128 + n0)*32 + ko);
      f16x8 b1 = *(const f16x8*)(W2sw + (size_t)(kb*128 + n0 + 16)*32 + ko);
#pragma unroll
      for (int m=0;m<4;++m){
        f16x8 a = *(const f16x8*)(bufH + (m*16 + tr)*HS + kb*32 + ko);
        acc[m][0] = __builtin_amdgcn_mfma_f32_16x16x32_f16(a, b0, acc[m][0], 0,0,0);
        acc[m][1] = __builtin_amdgcn_mfma_f32_16x16x32_f16(a, b1, acc[m][1], 0,0,0);
      }
    }
    float bb0 = b2v[n0], bb1 = b2v[n0+16];
#pragma unroll
    for (int m=0;m<4;++m){
#pragma unroll
      for (int r=0;r<4;++r){
        int ss = m*16 + (l>>4)*4 + r;
        buf[ss*HS + n0]      = (f16)fmaxf(acc[m][0][r] + bb0, 0.f);
        buf[ss*HS + n0 + 16] = (f16)fmaxf(acc[m][1][r] + bb1, 0.f);
      }
    }
  }
  __syncthreads();

  // ---------------- Phase E: layer3 + sigmoid ----------------
  {
    f32x4 acc = {0.f,0.f,0.f,0.f};
#pragma unroll
    for (int kb=0; kb<4; ++kb){
      f16x8 a = *(const f16x8*)(buf + (w*16 + tr)*HS + kb*32 + ko);
      f16x8 b = *(const f16x8*)(W3sw + (size_t)(kb*16 + tr)*32 + ko);
      acc = __builtin_amdgcn_mfma_f32_16x16x32_f16(a, b, acc, 0,0,0);
    }
    if (tr < 3){
      float bb = b3v[tr];
#pragma unroll
      for (int r=0;r<4;++r){
        float c = acc[r] + bb;
        out[(size_t)pmr[r]*4 + tr] = 1.f/(1.f + __expf(-c));
      }
    }
  }
}

extern "C" void kernel_launch(void* const* d_in, const int* in_sizes, int n_in,
                              void* d_out, int out_size, void* d_ws, size_t ws_size,
                              hipStream_t stream)
{
  const float* xin     = (const float*)d_in[0];
  const float* vmc_vec = (const float*)d_in[1];
  const float* vmc_mat = (const float*)d_in[2];
  const float* vmd_vec = (const float*)d_in[3];
  const float* vmd_mat = (const float*)d_in[4];
  const float* feat_w  = (const float*)d_in[5];
  const float* w1      = (const float*)d_in[6];
  const float* b1      = (const float*)d_in[7];
  const float* w2      = (const float*)d_in[8];
  const float* b2      = (const float*)d_in[9];
  const float* w3      = (const float*)d_in[10];
  const float* b3      = (const float*)d_in[11];
  float* out = (float*)d_out;

  char* ws = (char*)d_ws;
  f16*   Weff = (f16*)(ws + WOFF_WEFF);
  f16*   W1sw = (f16*)(ws + WOFF_W1SW);
  f16*   W2sw = (f16*)(ws + WOFF_W2SW);
  f16*   W3sw = (f16*)(ws + WOFF_W3SW);
  float* vd   = (float*)(ws + WOFF_VD);
  u32*   Tm   = (u32*)(ws + WOFF_TM);
  u32*   hist = (u32*)(ws + WOFF_HIST);
  u32*   cur  = (u32*)(ws + WOFF_CUR);
  u32*   keys = (u32*)(ws + WOFF_KEYS);
  u32*   perm = (u32*)(ws + WOFF_PERM);
  float* xs   = (float*)(ws + WOFF_XS);

  prep_k<<<64, 256, 0, stream>>>(feat_w, vmc_vec, vmd_vec, w1, w2, w3,
                                 Weff, W1sw, W2sw, W3sw, vd);
  pack_k<<<1800, 256, 0, stream>>>(vmc_mat, vmd_mat, Tm);

  if (ws_size >= (size_t)WS_NEED){
    zero_k<<<32, 1024, 0, stream>>>(hist);
    key_k<<<2048, 256, 0, stream>>>(xin, keys, hist);
    scan_k<<<1, 1024, 0, stream>>>(hist, cur);
    scatter_k<<<2048, 256, 0, stream>>>(xin, keys, cur, perm, xs);
    main_k<true><<<8192, 256, 0, stream>>>(xs, perm, Weff, W1sw, W2sw, W3sw, vd,
                                           (const uint4*)Tm, b1, b2, b3, out);
  } else {
    main_k<false><<<8192, 256, 0, stream>>>(xin, nullptr, Weff, W1sw, W2sw, W3sw, vd,
                                            (const uint4*)Tm, b1, b2, b3, out);
  }
}